// Round 6
// baseline (142.893 us; speedup 1.0000x reference)
//
#include <hip/hip_runtime.h>

typedef __attribute__((ext_vector_type(8))) short bf16x8;
typedef __attribute__((ext_vector_type(4))) float f32x4;

// RNE bf16 (epilogues — off critical path)
__device__ __forceinline__ unsigned short f2bf(float f) {
    unsigned int u = __builtin_bit_cast(unsigned int, f);
    unsigned int r = (u + 0x7FFFu + ((u >> 16) & 1u)) >> 16;
    return (unsigned short)r;
}
// round-half-up pack of two fp32 -> packed bf16x2 (cheap) — staging hot path
__device__ __forceinline__ unsigned int pkbf(float lo, float hi) {
    unsigned int ul = __builtin_bit_cast(unsigned int, lo) + 0x8000u;
    unsigned int uh = __builtin_bit_cast(unsigned int, hi) + 0x8000u;
    return (uh & 0xFFFF0000u) | (ul >> 16);
}
__device__ __forceinline__ float bf2f(unsigned short u) {
    unsigned int x = ((unsigned int)u) << 16;
    return __builtin_bit_cast(float, x);
}

__device__ __forceinline__ void gll16(const void* g, void* l) {
    __builtin_amdgcn_global_load_lds(
        (const __attribute__((address_space(1))) void*)g,
        (__attribute__((address_space(3))) void*)l, 16, 0, 0);
}

// ---------------------------------------------------------------------------
// kW: tiled transpose + fp32->bf16. src [b][R][C] f32 -> dstT [b][C][R] bf16.
// ---------------------------------------------------------------------------
__global__ __launch_bounds__(256) void transpose_cvt_kernel(
    const float* __restrict__ src, unsigned short* __restrict__ dstT,
    unsigned short* __restrict__ dstS, int R, int C)
{
    __shared__ float tile[64][65];
    const int b = blockIdx.z;
    const float* s = src + (size_t)b * R * C;
    const int r0 = blockIdx.x * 64, c0 = blockIdx.y * 64;
    const int t = threadIdx.x;
    const int r = t >> 2, cg = (t & 3) * 16;

    float v[16];
    const float4* p = reinterpret_cast<const float4*>(s + (size_t)(r0 + r) * C + c0 + cg);
#pragma unroll
    for (int i = 0; i < 4; ++i) {
        float4 q = p[i];
        v[4 * i + 0] = q.x; v[4 * i + 1] = q.y; v[4 * i + 2] = q.z; v[4 * i + 3] = q.w;
    }
#pragma unroll
    for (int i = 0; i < 16; ++i) tile[r][cg + i] = v[i];

    if (dstS) {
        unsigned int w[8];
#pragma unroll
        for (int i = 0; i < 8; ++i)
            w[i] = (unsigned)f2bf(v[2 * i]) | ((unsigned)f2bf(v[2 * i + 1]) << 16);
        unsigned int* d = reinterpret_cast<unsigned int*>(
            dstS + (size_t)b * R * C + (size_t)(r0 + r) * C + c0 + cg);
        *reinterpret_cast<uint4*>(d)     = make_uint4(w[0], w[1], w[2], w[3]);
        *reinterpret_cast<uint4*>(d + 4) = make_uint4(w[4], w[5], w[6], w[7]);
    }

    __syncthreads();

    const int cl = t >> 2, rg = (t & 3) * 16;
    unsigned int w[8];
#pragma unroll
    for (int i = 0; i < 8; ++i) {
        unsigned short lo = f2bf(tile[rg + 2 * i][cl]);
        unsigned short hi = f2bf(tile[rg + 2 * i + 1][cl]);
        w[i] = (unsigned)lo | ((unsigned)hi << 16);
    }
    unsigned int* d = reinterpret_cast<unsigned int*>(
        dstT + (size_t)b * R * C + (size_t)(c0 + cl) * R + r0 + rg);
    *reinterpret_cast<uint4*>(d)     = make_uint4(w[0], w[1], w[2], w[3]);
    *reinterpret_cast<uint4*>(d + 4) = make_uint4(w[4], w[5], w[6], w[7]);
}

// ---------------------------------------------------------------------------
// kPre: H = F@W1 + bias (bf16 row-major) and G^T = (F@W2)^T (bf16
// [batch][256][2048]). Unchanged (passed; ~8 µs).
// ---------------------------------------------------------------------------
__global__ __launch_bounds__(256, 2) void kpre_gemm(
    const float* __restrict__ F, const unsigned short* __restrict__ Wt,
    const float* __restrict__ bias, unsigned short* __restrict__ H,
    unsigned short* __restrict__ Gt)
{
    __shared__ __align__(16) short Fb[64 * 256];   // 32KB
    __shared__ __align__(16) short Wb[256 * 64];   // 32KB (+ G^T scratch)

    const int tid = threadIdx.x;
    const int lane = tid & 63, wid = tid >> 6;   // 4 waves
    const int lo = lane & 15, hi = lane >> 4;
    const int rb = blockIdx.x;                   // 0..511
    const int batch = rb >> 5;
    const int mb = (rb & 31) * 64;
    const size_t m0g = (size_t)rb * 64;

    {
        const int frow = tid >> 2, fq = tid & 3;
        const float* fp = F + (m0g + frow) * 256 + fq * 64;
#pragma unroll
        for (int g = 0; g < 2; ++g) {
            float4 q[8];
#pragma unroll
            for (int i = 0; i < 8; ++i)
                q[i] = reinterpret_cast<const float4*>(fp)[g * 8 + i];
#pragma unroll
            for (int j = 0; j < 4; ++j) {
                unsigned int w0 = pkbf(q[2*j].x,   q[2*j].y);
                unsigned int w1 = pkbf(q[2*j].z,   q[2*j].w);
                unsigned int w2 = pkbf(q[2*j+1].x, q[2*j+1].y);
                unsigned int w3 = pkbf(q[2*j+1].z, q[2*j+1].w);
                int slot = fq * 8 + g * 4 + j;
                int off = frow * 256 + ((slot ^ (frow & 7)) << 3);
                *reinterpret_cast<uint4*>(&Fb[off]) = make_uint4(w0, w1, w2, w3);
            }
        }
    }

    f32x4 acc[4][4];

#pragma unroll
    for (int pass = 0; pass < 2; ++pass) {
#pragma unroll
        for (int m = 0; m < 4; ++m)
#pragma unroll
            for (int n = 0; n < 4; ++n) acc[m][n] = (f32x4){0.f, 0.f, 0.f, 0.f};

        for (int kt = 0; kt < 4; ++kt) {
            const int kbase = pass * 256 + kt * 64;
#pragma unroll
            for (int it = 0; it < 8; ++it) {
                int si = it * 256 + tid;
                int row = si >> 3, slot = si & 7;
                const unsigned short* g = Wt + (size_t)row * 512 + kbase + ((slot ^ (row & 7)) << 3);
                gll16(g, Wb + (size_t)si * 8);
            }
            __syncthreads();

#pragma unroll
            for (int kk = 0; kk < 2; ++kk) {
                bf16x8 af[4], bw[4];
#pragma unroll
                for (int m = 0; m < 4; ++m) {
                    int row = m * 16 + lo;
                    int slot = kt * 8 + kk * 4 + hi;
                    af[m] = *reinterpret_cast<const bf16x8*>(&Fb[row * 256 + ((slot ^ (row & 7)) << 3)]);
                }
#pragma unroll
                for (int n = 0; n < 4; ++n) {
                    int row = wid * 64 + n * 16 + lo;
                    bw[n] = *reinterpret_cast<const bf16x8*>(&Wb[row * 64 + (((kk * 4 + hi) ^ (row & 7)) << 3)]);
                }
#pragma unroll
                for (int m = 0; m < 4; ++m)
#pragma unroll
                    for (int n = 0; n < 4; ++n)
                        acc[m][n] = __builtin_amdgcn_mfma_f32_16x16x32_bf16(af[m], bw[n], acc[m][n], 0, 0, 0);
            }
            __syncthreads();
        }

        if (pass == 0) {
            float bv[4];
#pragma unroll
            for (int n = 0; n < 4; ++n) bv[n] = bias[wid * 64 + n * 16 + lo];
            unsigned short* Hb = H + m0g * 256;
#pragma unroll
            for (int m = 0; m < 4; ++m)
#pragma unroll
                for (int n = 0; n < 4; ++n)
#pragma unroll
                    for (int j = 0; j < 4; ++j) {
                        int row = m * 16 + hi * 4 + j;
                        int col = wid * 64 + n * 16 + lo;
                        Hb[(size_t)row * 256 + col] = f2bf(acc[m][n][j] + bv[n]);
                    }
        } else {
            short* T = Wb + wid * 4096;
#pragma unroll
            for (int m = 0; m < 4; ++m)
#pragma unroll
                for (int n = 0; n < 4; ++n)
#pragma unroll
                    for (int j = 0; j < 4; ++j) {
                        int gr = m * 16 + hi * 4 + j;
                        int gc = n * 16 + lo;
                        int slot = gr >> 3, e = gr & 7;
                        T[gc * 64 + ((slot ^ (gc & 7)) << 3) + e] = f2bf(acc[m][n][j]);
                    }
            unsigned short* Gb = Gt + ((size_t)batch * 256 + wid * 64) * 2048 + mb;
#pragma unroll
            for (int i = 0; i < 8; ++i) {
                int f = i * 8 + (lane >> 3);
                int s = lane & 7;
                bf16x8 v = *reinterpret_cast<const bf16x8*>(&T[f * 64 + ((s ^ (f & 7)) << 3)]);
                *reinterpret_cast<bf16x8*>(Gb + (size_t)f * 2048 + s * 8) = v;
            }
        }
    }
}

// ---------------------------------------------------------------------------
// kMain: out = relu(H + A @ G). R5's counted-vmcnt double-buffer pipeline
// + K-ROTATION: block mt starts its K-loop at chunk (2*mt)%32 and wraps, so
// the 16 blocks per batch touch 16 DIFFERENT Gt chunks at any instant ->
// whole 1MB panel (2MB/XCD) stays LRU-hot in the 4MB L2; A lines stream
// through and die. Cuts Gt HBM traffic 268MB -> ~17MB (first touch).
// ---------------------------------------------------------------------------
__global__ __launch_bounds__(512, 2) void kmain_gemm(
    const float* __restrict__ A, const unsigned short* __restrict__ Gt,
    const unsigned short* __restrict__ H, float* __restrict__ out)
{
    __shared__ __align__(16) short Ab[2][128 * 64];   // 2 x 16KB
    __shared__ __align__(16) short Bb[2][256 * 64];   // 2 x 32KB

    const int tid = threadIdx.x;
    const int lane = tid & 63, wid = tid >> 6;
    const int wr = wid >> 2, wc = wid & 3;
    const int lo = lane & 15, hi = lane >> 4;

    const int bid = blockIdx.x;
    const int wg = ((bid & 7) << 5) | (bid >> 3);   // bijective, 256 % 8 == 0
    const int batch = wg >> 4;
    const int mt    = wg & 15;
    const int rot   = mt * 2;                        // k-chunk rotation offset

    const float* Abase = A + ((size_t)batch * 2048 + (size_t)mt * 128) * 2048;
    const unsigned short* Gbase = Gt + (size_t)batch * 256 * 2048;

    const int arow = tid >> 2;    // 0..127
    const int acg  = tid & 3;     // 16-float group along k

    auto kof = [&](int i) { return ((i + rot) & 31) << 6; };   // rotated k0

    f32x4 acc[4][4];
#pragma unroll
    for (int m = 0; m < 4; ++m)
#pragma unroll
        for (int n = 0; n < 4; ++n) acc[m][n] = (f32x4){0.f, 0.f, 0.f, 0.f};

    float4 qa0[4], qa1[4];   // two named prefetch sets (rule #20: static indexing)

    auto loadA = [&](float4* q, int k0) {
        const float4* p = reinterpret_cast<const float4*>(
            Abase + (size_t)arow * 2048 + k0 + acg * 16);
#pragma unroll
        for (int i = 0; i < 4; ++i) q[i] = p[i];
    };
    auto writeA = [&](int buf, const float4* q) {
        unsigned int w0 = pkbf(q[0].x, q[0].y), w1 = pkbf(q[0].z, q[0].w);
        unsigned int w2 = pkbf(q[1].x, q[1].y), w3 = pkbf(q[1].z, q[1].w);
        unsigned int w4 = pkbf(q[2].x, q[2].y), w5 = pkbf(q[2].z, q[2].w);
        unsigned int w6 = pkbf(q[3].x, q[3].y), w7 = pkbf(q[3].z, q[3].w);
        int slin = acg * 2;
        int off0 = arow * 64 + (((slin    ) ^ (arow & 7)) << 3);
        int off1 = arow * 64 + (((slin + 1) ^ (arow & 7)) << 3);
        *reinterpret_cast<uint4*>(&Ab[buf][off0]) = make_uint4(w0, w1, w2, w3);
        *reinterpret_cast<uint4*>(&Ab[buf][off1]) = make_uint4(w4, w5, w6, w7);
    };
    auto stageB = [&](int buf, int k0) {
#pragma unroll
        for (int it = 0; it < 4; ++it) {
            int si = it * 512 + tid;
            int row = si >> 3, slot = si & 7;
            const unsigned short* g = Gbase + (size_t)row * 2048 + k0 + ((slot ^ (row & 7)) << 3);
            gll16(g, &Bb[buf][(size_t)si * 8]);
        }
    };
    auto compute = [&](int buf) {
#pragma unroll
        for (int kk = 0; kk < 2; ++kk) {
            bf16x8 af[4], bfv[4];
#pragma unroll
            for (int m = 0; m < 4; ++m) {
                int row = wr * 64 + m * 16 + lo;
                af[m] = *reinterpret_cast<const bf16x8*>(
                    &Ab[buf][row * 64 + (((kk * 4 + hi) ^ (row & 7)) << 3)]);
            }
#pragma unroll
            for (int n = 0; n < 4; ++n) {
                int row = wc * 64 + n * 16 + lo;
                bfv[n] = *reinterpret_cast<const bf16x8*>(
                    &Bb[buf][row * 64 + (((kk * 4 + hi) ^ (row & 7)) << 3)]);
            }
            __builtin_amdgcn_s_setprio(1);
#pragma unroll
            for (int m = 0; m < 4; ++m)
#pragma unroll
                for (int n = 0; n < 4; ++n)
                    acc[m][n] = __builtin_amdgcn_mfma_f32_16x16x32_bf16(af[m], bfv[n], acc[m][n], 0, 0, 0);
            __builtin_amdgcn_s_setprio(0);
        }
    };

    // ---- prologue: fill tile 0+1 pipelines ----
    loadA(qa0, kof(0));            // A(0)            [vm: A0 x4]
    stageB(0, kof(0));             // B(0) -> Bb[0]   [vm: A0,gll0]
    writeA(0, qa0);                // waits vmcnt(4) -> A0 done; pack -> Ab[0]
    loadA(qa1, kof(1));            // A(1)            [vm: gll0, A1]
    asm volatile("s_waitcnt vmcnt(4) lgkmcnt(0)" ::: "memory");  // gll0 done
    __builtin_amdgcn_s_barrier();
    asm volatile("" ::: "memory");
    stageB(1, kof(1));             // B(1) -> Bb[1]   [vm: A1, gll1]

    // ---- steady: bodies t = 0..29, paired even/odd ----
    for (int tt = 0; tt < 15; ++tt) {
        const int t0 = tt * 2;
        // t even: cur=0
        writeA(1, qa1);                    // A(t+1) -> Ab[1]  (waits vmcnt(4))
        loadA(qa0, kof(t0 + 2));           // A(t+2) in flight
        compute(0);
        asm volatile("s_waitcnt vmcnt(4) lgkmcnt(0)" ::: "memory");  // gll(t+1) done, A(t+2) in flight
        __builtin_amdgcn_s_barrier();
        asm volatile("" ::: "memory");
        stageB(0, kof(t0 + 2));            // B(t+2) -> Bb[0]
        // t odd: cur=1
        writeA(0, qa0);                    // A(t+2) -> Ab[0]
        loadA(qa1, kof(t0 + 3));           // A(t+3)
        compute(1);
        asm volatile("s_waitcnt vmcnt(4) lgkmcnt(0)" ::: "memory");
        __builtin_amdgcn_s_barrier();
        asm volatile("" ::: "memory");
        stageB(1, kof(t0 + 3));            // B(t+3) -> Bb[1]
    }
    // ---- tail: t=30 (cur=0), t=31 (cur=1) ----
    writeA(1, qa1);                        // A(31) -> Ab[1]
    compute(0);
    asm volatile("s_waitcnt vmcnt(0) lgkmcnt(0)" ::: "memory");   // drain gll(31)
    __builtin_amdgcn_s_barrier();
    asm volatile("" ::: "memory");
    compute(1);

    // ---- epilogue: out = relu(acc + H) ----
    const size_t rowbase = (size_t)batch * 2048 + (size_t)mt * 128;
    const unsigned short* Hb = H + rowbase * 256;
    float* obase = out + rowbase * 256;
#pragma unroll
    for (int m = 0; m < 4; ++m) {
#pragma unroll
        for (int n = 0; n < 4; ++n) {
            int col = wc * 64 + n * 16 + lo;
#pragma unroll
            for (int j = 0; j < 4; ++j) {
                int row = wr * 64 + m * 16 + hi * 4 + j;
                float v = acc[m][n][j] + bf2f(Hb[(size_t)row * 256 + col]);
                obase[(size_t)row * 256 + col] = fmaxf(v, 0.f);
            }
        }
    }
}

// ---------------------------------------------------------------------------
extern "C" void kernel_launch(void* const* d_in, const int* in_sizes, int n_in,
                              void* d_out, int out_size, void* d_ws, size_t ws_size,
                              hipStream_t stream) {
    const float* features = (const float*)d_in[0];   // [16][2048][256]
    const float* A        = (const float*)d_in[1];   // [16][2048][2048]
    const float* weight   = (const float*)d_in[2];   // [512][256]
    const float* bias     = (const float*)d_in[3];   // [256]
    float* out = (float*)d_out;

    const size_t WT_B = (size_t)256 * 512 * 2;             // 256 KB
    const size_t H_B  = (size_t)32768 * 256 * 2;           // 16.78 MB
    const size_t GT_B = (size_t)16 * 256 * 2048 * 2;       // 16.78 MB
    if (ws_size < WT_B + H_B + GT_B) return;

    char* ws = (char*)d_ws;
    unsigned short* Wt = (unsigned short*)ws;
    unsigned short* H  = (unsigned short*)(ws + WT_B);
    unsigned short* Gt = (unsigned short*)(ws + WT_B + H_B);

    dim3 gW(512 / 64, 256 / 64, 1);
    transpose_cvt_kernel<<<gW, 256, 0, stream>>>(weight, Wt, nullptr, 512, 256);

    kpre_gemm<<<512, 256, 0, stream>>>(features, Wt, bias, H, Gt);

    kmain_gemm<<<256, 512, 0, stream>>>(A, Gt, H, out);
}

// Round 7
// 111.388 us; speedup vs baseline: 1.2828x; 1.2828x over previous
//
#include <hip/hip_runtime.h>

typedef __attribute__((ext_vector_type(8))) short bf16x8;
typedef __attribute__((ext_vector_type(4))) float f32x4;

// RNE bf16 (epilogues — off critical path)
__device__ __forceinline__ unsigned short f2bf(float f) {
    unsigned int u = __builtin_bit_cast(unsigned int, f);
    unsigned int r = (u + 0x7FFFu + ((u >> 16) & 1u)) >> 16;
    return (unsigned short)r;
}
// round-half-up pack of two fp32 -> packed bf16x2 (cheap) — staging hot path
__device__ __forceinline__ unsigned int pkbf(float lo, float hi) {
    unsigned int ul = __builtin_bit_cast(unsigned int, lo) + 0x8000u;
    unsigned int uh = __builtin_bit_cast(unsigned int, hi) + 0x8000u;
    return (uh & 0xFFFF0000u) | (ul >> 16);
}
__device__ __forceinline__ float bf2f(unsigned short u) {
    unsigned int x = ((unsigned int)u) << 16;
    return __builtin_bit_cast(float, x);
}

__device__ __forceinline__ void gll16(const void* g, void* l) {
    __builtin_amdgcn_global_load_lds(
        (const __attribute__((address_space(1))) void*)g,
        (__attribute__((address_space(3))) void*)l, 16, 0, 0);
}

// ---------------------------------------------------------------------------
// kW: tiled transpose + fp32->bf16. src [b][R][C] f32 -> dstT [b][C][R] bf16.
// ---------------------------------------------------------------------------
__global__ __launch_bounds__(256) void transpose_cvt_kernel(
    const float* __restrict__ src, unsigned short* __restrict__ dstT,
    unsigned short* __restrict__ dstS, int R, int C)
{
    __shared__ float tile[64][65];
    const int b = blockIdx.z;
    const float* s = src + (size_t)b * R * C;
    const int r0 = blockIdx.x * 64, c0 = blockIdx.y * 64;
    const int t = threadIdx.x;
    const int r = t >> 2, cg = (t & 3) * 16;

    float v[16];
    const float4* p = reinterpret_cast<const float4*>(s + (size_t)(r0 + r) * C + c0 + cg);
#pragma unroll
    for (int i = 0; i < 4; ++i) {
        float4 q = p[i];
        v[4 * i + 0] = q.x; v[4 * i + 1] = q.y; v[4 * i + 2] = q.z; v[4 * i + 3] = q.w;
    }
#pragma unroll
    for (int i = 0; i < 16; ++i) tile[r][cg + i] = v[i];

    if (dstS) {
        unsigned int w[8];
#pragma unroll
        for (int i = 0; i < 8; ++i)
            w[i] = (unsigned)f2bf(v[2 * i]) | ((unsigned)f2bf(v[2 * i + 1]) << 16);
        unsigned int* d = reinterpret_cast<unsigned int*>(
            dstS + (size_t)b * R * C + (size_t)(r0 + r) * C + c0 + cg);
        *reinterpret_cast<uint4*>(d)     = make_uint4(w[0], w[1], w[2], w[3]);
        *reinterpret_cast<uint4*>(d + 4) = make_uint4(w[4], w[5], w[6], w[7]);
    }

    __syncthreads();

    const int cl = t >> 2, rg = (t & 3) * 16;
    unsigned int w[8];
#pragma unroll
    for (int i = 0; i < 8; ++i) {
        unsigned short lo = f2bf(tile[rg + 2 * i][cl]);
        unsigned short hi = f2bf(tile[rg + 2 * i + 1][cl]);
        w[i] = (unsigned)lo | ((unsigned)hi << 16);
    }
    unsigned int* d = reinterpret_cast<unsigned int*>(
        dstT + (size_t)b * R * C + (size_t)(c0 + cl) * R + r0 + rg);
    *reinterpret_cast<uint4*>(d)     = make_uint4(w[0], w[1], w[2], w[3]);
    *reinterpret_cast<uint4*>(d + 4) = make_uint4(w[4], w[5], w[6], w[7]);
}

// ---------------------------------------------------------------------------
// kPre: H = F@W1 + bias (bf16 row-major) and G^T = (F@W2)^T (bf16
// [batch][256][2048]). Unchanged (passed; small).
// ---------------------------------------------------------------------------
__global__ __launch_bounds__(256, 2) void kpre_gemm(
    const float* __restrict__ F, const unsigned short* __restrict__ Wt,
    const float* __restrict__ bias, unsigned short* __restrict__ H,
    unsigned short* __restrict__ Gt)
{
    __shared__ __align__(16) short Fb[64 * 256];   // 32KB
    __shared__ __align__(16) short Wb[256 * 64];   // 32KB (+ G^T scratch)

    const int tid = threadIdx.x;
    const int lane = tid & 63, wid = tid >> 6;   // 4 waves
    const int lo = lane & 15, hi = lane >> 4;
    const int rb = blockIdx.x;                   // 0..511
    const int batch = rb >> 5;
    const int mb = (rb & 31) * 64;
    const size_t m0g = (size_t)rb * 64;

    {
        const int frow = tid >> 2, fq = tid & 3;
        const float* fp = F + (m0g + frow) * 256 + fq * 64;
#pragma unroll
        for (int g = 0; g < 2; ++g) {
            float4 q[8];
#pragma unroll
            for (int i = 0; i < 8; ++i)
                q[i] = reinterpret_cast<const float4*>(fp)[g * 8 + i];
#pragma unroll
            for (int j = 0; j < 4; ++j) {
                unsigned int w0 = pkbf(q[2*j].x,   q[2*j].y);
                unsigned int w1 = pkbf(q[2*j].z,   q[2*j].w);
                unsigned int w2 = pkbf(q[2*j+1].x, q[2*j+1].y);
                unsigned int w3 = pkbf(q[2*j+1].z, q[2*j+1].w);
                int slot = fq * 8 + g * 4 + j;
                int off = frow * 256 + ((slot ^ (frow & 7)) << 3);
                *reinterpret_cast<uint4*>(&Fb[off]) = make_uint4(w0, w1, w2, w3);
            }
        }
    }

    f32x4 acc[4][4];

#pragma unroll
    for (int pass = 0; pass < 2; ++pass) {
#pragma unroll
        for (int m = 0; m < 4; ++m)
#pragma unroll
            for (int n = 0; n < 4; ++n) acc[m][n] = (f32x4){0.f, 0.f, 0.f, 0.f};

        for (int kt = 0; kt < 4; ++kt) {
            const int kbase = pass * 256 + kt * 64;
#pragma unroll
            for (int it = 0; it < 8; ++it) {
                int si = it * 256 + tid;
                int row = si >> 3, slot = si & 7;
                const unsigned short* g = Wt + (size_t)row * 512 + kbase + ((slot ^ (row & 7)) << 3);
                gll16(g, Wb + (size_t)si * 8);
            }
            __syncthreads();

#pragma unroll
            for (int kk = 0; kk < 2; ++kk) {
                bf16x8 af[4], bw[4];
#pragma unroll
                for (int m = 0; m < 4; ++m) {
                    int row = m * 16 + lo;
                    int slot = kt * 8 + kk * 4 + hi;
                    af[m] = *reinterpret_cast<const bf16x8*>(&Fb[row * 256 + ((slot ^ (row & 7)) << 3)]);
                }
#pragma unroll
                for (int n = 0; n < 4; ++n) {
                    int row = wid * 64 + n * 16 + lo;
                    bw[n] = *reinterpret_cast<const bf16x8*>(&Wb[row * 64 + (((kk * 4 + hi) ^ (row & 7)) << 3)]);
                }
#pragma unroll
                for (int m = 0; m < 4; ++m)
#pragma unroll
                    for (int n = 0; n < 4; ++n)
                        acc[m][n] = __builtin_amdgcn_mfma_f32_16x16x32_bf16(af[m], bw[n], acc[m][n], 0, 0, 0);
            }
            __syncthreads();
        }

        if (pass == 0) {
            float bv[4];
#pragma unroll
            for (int n = 0; n < 4; ++n) bv[n] = bias[wid * 64 + n * 16 + lo];
            unsigned short* Hb = H + m0g * 256;
#pragma unroll
            for (int m = 0; m < 4; ++m)
#pragma unroll
                for (int n = 0; n < 4; ++n)
#pragma unroll
                    for (int j = 0; j < 4; ++j) {
                        int row = m * 16 + hi * 4 + j;
                        int col = wid * 64 + n * 16 + lo;
                        Hb[(size_t)row * 256 + col] = f2bf(acc[m][n][j] + bv[n]);
                    }
        } else {
            short* T = Wb + wid * 4096;
#pragma unroll
            for (int m = 0; m < 4; ++m)
#pragma unroll
                for (int n = 0; n < 4; ++n)
#pragma unroll
                    for (int j = 0; j < 4; ++j) {
                        int gr = m * 16 + hi * 4 + j;
                        int gc = n * 16 + lo;
                        int slot = gr >> 3, e = gr & 7;
                        T[gc * 64 + ((slot ^ (gc & 7)) << 3) + e] = f2bf(acc[m][n][j]);
                    }
            unsigned short* Gb = Gt + ((size_t)batch * 256 + wid * 64) * 2048 + mb;
#pragma unroll
            for (int i = 0; i < 8; ++i) {
                int f = i * 8 + (lane >> 3);
                int s = lane & 7;
                bf16x8 v = *reinterpret_cast<const bf16x8*>(&T[f * 64 + ((s ^ (f & 7)) << 3)]);
                *reinterpret_cast<bf16x8*>(Gb + (size_t)f * 2048 + s * 8) = v;
            }
        }
    }
}

// ---------------------------------------------------------------------------
// kMain: out = relu(H + A @ G). R5 counted-vmcnt dbuf pipeline, rotation
// REVERTED (R6: -30µs), and the A-load pattern re-coalesced: per instruction,
// lanes 0-3 now cover ONE dense 64B sector (q[i] = p4[acg + 4*i]) instead of
// four quarter-used sectors (old: p[i] at acg*64B) -> 4x fewer vmem sector
// requests on the 268MB A stream (R6 counters: vmem request-bound, 1.3TB/s
// with both pipes idle).
// ---------------------------------------------------------------------------
__global__ __launch_bounds__(512, 2) void kmain_gemm(
    const float* __restrict__ A, const unsigned short* __restrict__ Gt,
    const unsigned short* __restrict__ H, float* __restrict__ out)
{
    __shared__ __align__(16) short Ab[2][128 * 64];   // 2 x 16KB
    __shared__ __align__(16) short Bb[2][256 * 64];   // 2 x 32KB

    const int tid = threadIdx.x;
    const int lane = tid & 63, wid = tid >> 6;
    const int wr = wid >> 2, wc = wid & 3;
    const int lo = lane & 15, hi = lane >> 4;

    const int bid = blockIdx.x;
    const int wg = ((bid & 7) << 5) | (bid >> 3);   // bijective, 256 % 8 == 0
    const int batch = wg >> 4;
    const int mt    = wg & 15;

    const float* Abase = A + ((size_t)batch * 2048 + (size_t)mt * 128) * 2048;
    const unsigned short* Gbase = Gt + (size_t)batch * 256 * 2048;

    const int arow = tid >> 2;    // 0..127
    const int acg  = tid & 3;     // 16B sub-column within the 64B row-chunk

    f32x4 acc[4][4];
#pragma unroll
    for (int m = 0; m < 4; ++m)
#pragma unroll
        for (int n = 0; n < 4; ++n) acc[m][n] = (f32x4){0.f, 0.f, 0.f, 0.f};

    float4 qa0[4], qa1[4];   // two named prefetch sets (rule #20: static indexing)

    // coalesced: instruction i covers a dense 64B sector per 4 lanes
    auto loadA = [&](float4* q, int k0) {
        const float4* p4 = reinterpret_cast<const float4*>(
            Abase + (size_t)arow * 2048 + k0);
#pragma unroll
        for (int i = 0; i < 4; ++i) q[i] = p4[acg + 4 * i];
    };
    // q[i] holds cols [acg*4 + 16i, +4) -> 8B half-slot h = acg + 4i
    auto writeA = [&](int buf, const float4* q) {
#pragma unroll
        for (int i = 0; i < 4; ++i) {
            uint2 w;
            w.x = pkbf(q[i].x, q[i].y);
            w.y = pkbf(q[i].z, q[i].w);
            int s = 2 * i + (acg >> 1);           // 16B slot index (0..7)
            int off = arow * 64 + ((s ^ (arow & 7)) << 3) + (acg & 1) * 4;  // elems
            *reinterpret_cast<uint2*>(&Ab[buf][off]) = w;
        }
    };
    auto stageB = [&](int buf, int k0) {
#pragma unroll
        for (int it = 0; it < 4; ++it) {
            int si = it * 512 + tid;
            int row = si >> 3, slot = si & 7;
            const unsigned short* g = Gbase + (size_t)row * 2048 + k0 + ((slot ^ (row & 7)) << 3);
            gll16(g, &Bb[buf][(size_t)si * 8]);
        }
    };
    auto compute = [&](int buf) {
#pragma unroll
        for (int kk = 0; kk < 2; ++kk) {
            bf16x8 af[4], bfv[4];
#pragma unroll
            for (int m = 0; m < 4; ++m) {
                int row = wr * 64 + m * 16 + lo;
                af[m] = *reinterpret_cast<const bf16x8*>(
                    &Ab[buf][row * 64 + (((kk * 4 + hi) ^ (row & 7)) << 3)]);
            }
#pragma unroll
            for (int n = 0; n < 4; ++n) {
                int row = wc * 64 + n * 16 + lo;
                bfv[n] = *reinterpret_cast<const bf16x8*>(
                    &Bb[buf][row * 64 + (((kk * 4 + hi) ^ (row & 7)) << 3)]);
            }
            __builtin_amdgcn_s_setprio(1);
#pragma unroll
            for (int m = 0; m < 4; ++m)
#pragma unroll
                for (int n = 0; n < 4; ++n)
                    acc[m][n] = __builtin_amdgcn_mfma_f32_16x16x32_bf16(af[m], bfv[n], acc[m][n], 0, 0, 0);
            __builtin_amdgcn_s_setprio(0);
        }
    };

    // ---- prologue: fill tile 0+1 pipelines ----
    loadA(qa0, 0);                 // A(0)            [vm: A0 x4]
    stageB(0, 0);                  // B(0) -> Bb[0]   [vm: A0,gll0]
    writeA(0, qa0);                // waits A0 done (compiler vmcnt); pack -> Ab[0]
    loadA(qa1, 64);                // A(1)            [vm: gll0, A1]
    asm volatile("s_waitcnt vmcnt(4) lgkmcnt(0)" ::: "memory");  // gll0 done
    __builtin_amdgcn_s_barrier();
    asm volatile("" ::: "memory");
    stageB(1, 64);                 // B(1) -> Bb[1]   [vm: A1, gll1]

    // ---- steady: bodies t = 0..29, paired even/odd ----
    for (int tt = 0; tt < 15; ++tt) {
        const int t0 = tt * 2;
        // t even: cur=0
        writeA(1, qa1);                    // A(t+1) -> Ab[1]
        loadA(qa0, (t0 + 2) * 64);         // A(t+2) in flight
        compute(0);
        asm volatile("s_waitcnt vmcnt(4) lgkmcnt(0)" ::: "memory");  // gll(t+1) done
        __builtin_amdgcn_s_barrier();
        asm volatile("" ::: "memory");
        stageB(0, (t0 + 2) * 64);          // B(t+2) -> Bb[0]
        // t odd: cur=1
        writeA(0, qa0);                    // A(t+2) -> Ab[0]
        loadA(qa1, (t0 + 3) * 64);         // A(t+3)
        compute(1);
        asm volatile("s_waitcnt vmcnt(4) lgkmcnt(0)" ::: "memory");
        __builtin_amdgcn_s_barrier();
        asm volatile("" ::: "memory");
        stageB(1, (t0 + 3) * 64);          // B(t+3) -> Bb[1]
    }
    // ---- tail: t=30 (cur=0), t=31 (cur=1) ----
    writeA(1, qa1);                        // A(31) -> Ab[1]
    compute(0);
    asm volatile("s_waitcnt vmcnt(0) lgkmcnt(0)" ::: "memory");   // drain gll(31)
    __builtin_amdgcn_s_barrier();
    asm volatile("" ::: "memory");
    compute(1);

    // ---- epilogue: out = relu(acc + H) ----
    const size_t rowbase = (size_t)batch * 2048 + (size_t)mt * 128;
    const unsigned short* Hb = H + rowbase * 256;
    float* obase = out + rowbase * 256;
#pragma unroll
    for (int m = 0; m < 4; ++m) {
#pragma unroll
        for (int n = 0; n < 4; ++n) {
            int col = wc * 64 + n * 16 + lo;
#pragma unroll
            for (int j = 0; j < 4; ++j) {
                int row = wr * 64 + m * 16 + hi * 4 + j;
                float v = acc[m][n][j] + bf2f(Hb[(size_t)row * 256 + col]);
                obase[(size_t)row * 256 + col] = fmaxf(v, 0.f);
            }
        }
    }
}

// ---------------------------------------------------------------------------
extern "C" void kernel_launch(void* const* d_in, const int* in_sizes, int n_in,
                              void* d_out, int out_size, void* d_ws, size_t ws_size,
                              hipStream_t stream) {
    const float* features = (const float*)d_in[0];   // [16][2048][256]
    const float* A        = (const float*)d_in[1];   // [16][2048][2048]
    const float* weight   = (const float*)d_in[2];   // [512][256]
    const float* bias     = (const float*)d_in[3];   // [256]
    float* out = (float*)d_out;

    const size_t WT_B = (size_t)256 * 512 * 2;             // 256 KB
    const size_t H_B  = (size_t)32768 * 256 * 2;           // 16.78 MB
    const size_t GT_B = (size_t)16 * 256 * 2048 * 2;       // 16.78 MB
    if (ws_size < WT_B + H_B + GT_B) return;

    char* ws = (char*)d_ws;
    unsigned short* Wt = (unsigned short*)ws;
    unsigned short* H  = (unsigned short*)(ws + WT_B);
    unsigned short* Gt = (unsigned short*)(ws + WT_B + H_B);

    dim3 gW(512 / 64, 256 / 64, 1);
    transpose_cvt_kernel<<<gW, 256, 0, stream>>>(weight, Wt, nullptr, 512, 256);

    kpre_gemm<<<512, 256, 0, stream>>>(features, Wt, bias, H, Gt);

    kmain_gemm<<<256, 512, 0, stream>>>(A, Gt, H, out);
}